// Round 2
// baseline (914.582 us; speedup 1.0000x reference)
//
#include <hip/hip_runtime.h>
#include <cstdint>
#include <cstddef>

// ArcFace: e=l2norm(emb) [1024,512]; w=l2norm(weight) [100000,512];
// cos = clip(e@w^T, -1, 1); at (r, labels[r]): cos(theta+0.5); out = 30*logits.
// Margin closed form: cos(theta+M) = cosM*c - sinM*sqrt(1-c^2)  (theta in [0,pi]).
//
// GEMM strategy: NO LDS, NO barriers. K=512 is short; A (1 MB bf16) is
// L2-resident; B (W) fragments are loaded straight from global as 16B
// dwordx4 (the mfma_16x16x32 B-fragment IS 8 contiguous k-elements of one
// W row). Latency is hidden by occupancy (16 waves/CU) + full K unroll.
// XCD-swizzled 1D grid keeps each panel's 8 M-blocks on one XCD's L2.
// Output stores are nontemporal so the 400 MB stream doesn't evict W from L2.

constexpr int N_ROWS  = 1024;
constexpr int DIM     = 512;
constexpr int C_CLS   = 100000;
constexpr int NPANEL  = 392;     // panels of 256 cols -> 100352 padded; 392 = 8*49
constexpr int MTILES  = 8;       // 1024 / 128

#define COS_M 0.87758256189037271612f
#define SIN_M 0.47942553860420300027f

typedef __attribute__((ext_vector_type(8))) __bf16 bf16x8;
typedef __attribute__((ext_vector_type(4))) float  floatx4;

__device__ inline unsigned short f2bf(float f) {
    unsigned int u = __float_as_uint(f);
    u += 0x7FFFu + ((u >> 16) & 1u);   // round-to-nearest-even
    return (unsigned short)(u >> 16);
}

__device__ inline float wave_reduce_sum(float v) {
    v += __shfl_xor(v, 32, 64);
    v += __shfl_xor(v, 16, 64);
    v += __shfl_xor(v, 8, 64);
    v += __shfl_xor(v, 4, 64);
    v += __shfl_xor(v, 2, 64);
    v += __shfl_xor(v, 1, 64);
    return v;
}

// One wave per row: l2-normalize f32 row -> bf16 row.
__global__ __launch_bounds__(256) void normalize_rows(
    const float* __restrict__ in, unsigned short* __restrict__ out, int rows) {
    int wave = (int)((blockIdx.x * 256u + threadIdx.x) >> 6);
    int lane = threadIdx.x & 63;
    if (wave >= rows) return;

    const float4* rp = (const float4*)(in + (size_t)wave * DIM);
    float4 x0 = rp[lane];        // cols 4*lane .. +4
    float4 x1 = rp[64 + lane];   // cols 256 + 4*lane .. +4
    float s = x0.x*x0.x + x0.y*x0.y + x0.z*x0.z + x0.w*x0.w
            + x1.x*x1.x + x1.y*x1.y + x1.z*x1.z + x1.w*x1.w;
    s = wave_reduce_sum(s);
    float inv = 1.0f / fmaxf(sqrtf(s), 1e-12f);
    unsigned short* orow = out + (size_t)wave * DIM;
    ushort4 o0, o1;
    o0.x = f2bf(x0.x * inv); o0.y = f2bf(x0.y * inv);
    o0.z = f2bf(x0.z * inv); o0.w = f2bf(x0.w * inv);
    o1.x = f2bf(x1.x * inv); o1.y = f2bf(x1.y * inv);
    o1.z = f2bf(x1.z * inv); o1.w = f2bf(x1.w * inv);
    ((ushort4*)orow)[lane]      = o0;
    ((ushort4*)orow)[64 + lane] = o1;
}

// 128x256 tile, 8 waves (2M x 4N), each wave owns a 64x64 output tile.
// All fragments loaded directly from global (L1/L2); zero LDS tiles.
__global__ __launch_bounds__(512, 2) void arcface_gemm(
    const unsigned short* __restrict__ A,
    const unsigned short* __restrict__ Wn,
    const int* __restrict__ labels,
    float* __restrict__ out) {
    __shared__ int labs[128];

    const int tid  = threadIdx.x;
    const int lane = tid & 63;
    const int wv   = tid >> 6;       // 0..7
    const int wr   = wv >> 2;        // 0..1  (64-row quadrant)
    const int wc   = wv & 3;         // 0..3  (64-col quadrant)
    const int mrow = lane & 15;
    const int kq8  = lane >> 4;      // 0..3: this lane's 8-elem k-chunk

    // Bijective XCD swizzle: 3136 blocks = 8 XCDs x 392; each XCD gets 49
    // contiguous panels; the 8 M-blocks of a panel are 8 apart in bid.
    const int bid   = blockIdx.x;
    const int xcd   = bid & 7;
    const int s     = bid >> 3;                  // 0..391
    const int panel = xcd * (NPANEL / 8) + (s >> 3);
    const int mtile = s & 7;
    const int mbase = mtile * 128;
    const int nbase = panel * 256;

    if (tid < 128) labs[tid] = labels[mbase + tid];
    __syncthreads();   // the only barrier in the kernel

    // Fragment base pointers (k-offsets folded into the unrolled loop as
    // compile-time immediates: ks*32 elems = ks*64 bytes, max 960 < 4 KiB).
    const unsigned short* pa[4];
    const unsigned short* pb[4];
    #pragma unroll
    for (int i = 0; i < 4; i++) {
        int ra = mbase + wr * 64 + i * 16 + mrow;
        pa[i] = A + (size_t)ra * DIM + kq8 * 8;
        int rb = nbase + wc * 64 + i * 16 + mrow;
        if (rb > C_CLS - 1) rb = C_CLS - 1;      // clamp padded cols (stores guarded)
        pb[i] = Wn + (size_t)rb * DIM + kq8 * 8;
    }

    floatx4 acc[4][4];
    #pragma unroll
    for (int i = 0; i < 4; i++)
        #pragma unroll
        for (int j = 0; j < 4; j++)
            acc[i][j] = (floatx4){0.f, 0.f, 0.f, 0.f};

    #pragma unroll
    for (int ks = 0; ks < 16; ks++) {
        bf16x8 af[4], bfr[4];
        #pragma unroll
        for (int i = 0; i < 4; i++)
            af[i] = *(const bf16x8*)(pa[i] + ks * 32);
        #pragma unroll
        for (int j = 0; j < 4; j++)
            bfr[j] = *(const bf16x8*)(pb[j] + ks * 32);
        #pragma unroll
        for (int i = 0; i < 4; i++)
            #pragma unroll
            for (int j = 0; j < 4; j++)
                acc[i][j] = __builtin_amdgcn_mfma_f32_16x16x32_bf16(
                    af[i], bfr[j], acc[i][j], 0, 0, 0);
    }

    // Epilogue: C/D layout col = lane&15, row = (lane>>4)*4 + reg
    const int col0 = nbase + wc * 64 + mrow;
    #pragma unroll
    for (int i = 0; i < 4; i++) {
        const int rbase = wr * 64 + i * 16 + (lane >> 4) * 4;
        #pragma unroll
        for (int r = 0; r < 4; r++) {
            const int row  = rbase + r;
            const int grow = mbase + row;
            const int lab  = labs[row];
            float* orow = out + (size_t)grow * C_CLS;
            #pragma unroll
            for (int j = 0; j < 4; j++) {
                const int gc = col0 + j * 16;
                if (gc < C_CLS) {
                    float c = acc[i][j][r];
                    c = fminf(1.0f, fmaxf(-1.0f, c));
                    float v = c;
                    if (gc == lab) {
                        v = COS_M * c - SIN_M * sqrtf(fmaxf(0.0f, 1.0f - c * c));
                    }
                    __builtin_nontemporal_store(30.0f * v, &orow[gc]);
                }
            }
        }
    }
}

extern "C" void kernel_launch(void* const* d_in, const int* in_sizes, int n_in,
                              void* d_out, int out_size, void* d_ws, size_t ws_size,
                              hipStream_t stream) {
    const float* emb    = (const float*)d_in[0];
    const float* wgt    = (const float*)d_in[1];
    const int*   labels = (const int*)d_in[2];
    float*       out    = (float*)d_out;

    unsigned short* An = (unsigned short*)d_ws;                         // 1024*512 bf16 = 1 MiB
    unsigned short* Wn = (unsigned short*)((char*)d_ws + (size_t)N_ROWS * DIM * 2);  // 100000*512 bf16

    normalize_rows<<<N_ROWS / 4, 256, 0, stream>>>(emb, An, N_ROWS);
    normalize_rows<<<C_CLS / 4, 256, 0, stream>>>(wgt, Wn, C_CLS);
    arcface_gemm<<<dim3(MTILES * NPANEL), 512, 0, stream>>>(An, Wn, labels, out);
}

// Round 3
// 758.010 us; speedup vs baseline: 1.2066x; 1.2066x over previous
//
#include <hip/hip_runtime.h>
#include <cstdint>
#include <cstddef>

// ArcFace: e=l2norm(emb) [1024,512]; w=l2norm(weight) [100000,512];
// cos = clip(e@w^T, -1, 1); at (r, labels[r]): cos(theta+0.5); out = 30*logits.
// Margin closed form: cos(theta+M) = cosM*c - sinM*sqrt(1-c^2)  (theta in [0,pi]).
//
// GEMM: 128x256 tile, 8 waves (2Mx4N), bf16 LDS double-buffered with the
// T3 minimal 2-phase pipeline (prefetch tile t+1, compute tile t, ONE
// __syncthreads per K-step so the vmcnt(0) drain overlaps compute).
// LDS is laid out in MFMA-fragment order: the per-lane GLOBAL address of
// each global_load_lds is chosen so that lane l's 16 B land exactly where
// fragment-lane l reads -> all ds_reads are base + lane*16 (stride-1
// b128, zero bank conflicts, zero swizzle math).
// Bijective XCD swizzle keeps the 8 M-blocks of a W panel on one XCD.

constexpr int N_ROWS  = 1024;
constexpr int DIM     = 512;
constexpr int C_CLS   = 100000;
constexpr int NPANEL  = 392;     // 256-col panels -> 100352 padded; 392 = 8*49
constexpr int MTILES  = 8;       // 1024 / 128

#define COS_M 0.87758256189037271612f
#define SIN_M 0.47942553860420300027f

typedef __attribute__((ext_vector_type(8))) __bf16 bf16x8;
typedef __attribute__((ext_vector_type(4))) float  floatx4;

__device__ inline unsigned short f2bf(float f) {
    unsigned int u = __float_as_uint(f);
    u += 0x7FFFu + ((u >> 16) & 1u);   // round-to-nearest-even
    return (unsigned short)(u >> 16);
}

__device__ inline float wave_reduce_sum(float v) {
    v += __shfl_xor(v, 32, 64);
    v += __shfl_xor(v, 16, 64);
    v += __shfl_xor(v, 8, 64);
    v += __shfl_xor(v, 4, 64);
    v += __shfl_xor(v, 2, 64);
    v += __shfl_xor(v, 1, 64);
    return v;
}

__device__ inline void async16(const void* g, void* l) {
    __builtin_amdgcn_global_load_lds(
        (const __attribute__((address_space(1))) void*)g,
        (__attribute__((address_space(3))) void*)l,
        16, 0, 0);
}

// One wave per row: l2-normalize f32 row -> bf16 row.
__global__ __launch_bounds__(256) void normalize_rows(
    const float* __restrict__ in, unsigned short* __restrict__ out, int rows) {
    int wave = (int)((blockIdx.x * 256u + threadIdx.x) >> 6);
    int lane = threadIdx.x & 63;
    if (wave >= rows) return;

    const float4* rp = (const float4*)(in + (size_t)wave * DIM);
    float4 x0 = rp[lane];        // cols 4*lane .. +4
    float4 x1 = rp[64 + lane];   // cols 256 + 4*lane .. +4
    float s = x0.x*x0.x + x0.y*x0.y + x0.z*x0.z + x0.w*x0.w
            + x1.x*x1.x + x1.y*x1.y + x1.z*x1.z + x1.w*x1.w;
    s = wave_reduce_sum(s);
    float inv = 1.0f / fmaxf(sqrtf(s), 1e-12f);
    unsigned short* orow = out + (size_t)wave * DIM;
    ushort4 o0, o1;
    o0.x = f2bf(x0.x * inv); o0.y = f2bf(x0.y * inv);
    o0.z = f2bf(x0.z * inv); o0.w = f2bf(x0.w * inv);
    o1.x = f2bf(x1.x * inv); o1.y = f2bf(x1.y * inv);
    o1.z = f2bf(x1.z * inv); o1.w = f2bf(x1.w * inv);
    ((ushort4*)orow)[lane]      = o0;
    ((ushort4*)orow)[64 + lane] = o1;
}

// 128x256 tile GEMM. A [1024,512] bf16 (pre-normalized), Wn [100000,512] bf16
// (pre-normalized), out = 30*clip(A@Wn^T) with margin at (r, labels[r]).
__global__ __launch_bounds__(512, 4) void arcface_gemm(
    const unsigned short* __restrict__ A,
    const unsigned short* __restrict__ Wn,
    const int* __restrict__ labels,
    float* __restrict__ out) {
    // Fragment-ordered LDS: 16-row group g, k-chunk kq, row-in-group mrow.
    // ushort index = g*512 + (kq*16 + mrow)*8 = g*512 + lane*8 for the reader.
    __shared__ unsigned short Asm[2][4096];  // 128 rows x 32 k  (8 groups)
    __shared__ unsigned short Bsm[2][8192];  // 256 rows x 32 k  (16 groups)
    __shared__ int labs[128];

    const int tid  = threadIdx.x;
    const int lane = tid & 63;
    const int wv   = tid >> 6;       // 0..7
    const int wr   = wv >> 2;        // 0..1  (64-row quadrant)
    const int wc   = wv & 3;         // 0..3  (64-col quadrant)
    const int mrow = lane & 15;

    // Bijective XCD swizzle: 3136 blocks = 8 XCDs x 392; 49 panels/XCD; the
    // 8 M-blocks of a panel are 8 apart in bid -> same XCD, adjacent dispatch.
    const int bid   = blockIdx.x;
    const int xcd   = bid & 7;
    const int s     = bid >> 3;                  // 0..391
    const int panel = xcd * (NPANEL / 8) + (s >> 3);
    const int mtile = s & 7;
    const int mbase = mtile * 128;
    const int nbase = panel * 256;

    if (tid < 128) labs[tid] = labels[mbase + tid];

    // ---- staging sources: lane l of group g loads row g*16+(l&15),
    //      k-chunk (l>>4); LDS dest is linear tid*16B == fragment order.
    const int sg    = tid >> 6;                  // group 0..7 (this wave's)
    const int smrow = lane & 15;
    const int skq   = lane >> 4;
    const unsigned short* aSrc = A + (size_t)(mbase + sg * 16 + smrow) * DIM + skq * 8;
    int brow0 = nbase + sg * 16 + smrow;
    int brow1 = nbase + 128 + sg * 16 + smrow;
    if (brow0 > C_CLS - 1) brow0 = C_CLS - 1;    // clamp padded cols (stores guarded)
    if (brow1 > C_CLS - 1) brow1 = C_CLS - 1;
    const unsigned short* bSrc0 = Wn + (size_t)brow0 * DIM + skq * 8;
    const unsigned short* bSrc1 = Wn + (size_t)brow1 * DIM + skq * 8;

    #define STAGE(buf, k0)                                         \
        do {                                                       \
            async16(aSrc  + (k0), &Asm[buf][tid * 8]);             \
            async16(bSrc0 + (k0), &Bsm[buf][tid * 8]);             \
            async16(bSrc1 + (k0), &Bsm[buf][4096 + tid * 8]);      \
        } while (0)

    floatx4 acc[4][4];
    #pragma unroll
    for (int i = 0; i < 4; i++)
        #pragma unroll
        for (int j = 0; j < 4; j++)
            acc[i][j] = (floatx4){0.f, 0.f, 0.f, 0.f};

    // Fragment read offsets (ushort idx): group (wr*4+i) / (wc*4+j), + lane*8.
    const int aoff = wr * 2048 + lane * 8;
    const int boff = wc * 2048 + lane * 8;

    STAGE(0, 0);
    __syncthreads();                 // tile 0 resident

    int cur = 0;
    for (int t = 0; t < 15; t++) {
        STAGE(cur ^ 1, (t + 1) * 32);          // prefetch next tile (async)
        bf16x8 af[4], bfr[4];
        #pragma unroll
        for (int i = 0; i < 4; i++)
            af[i] = *(const bf16x8*)&Asm[cur][aoff + i * 512];
        #pragma unroll
        for (int j = 0; j < 4; j++)
            bfr[j] = *(const bf16x8*)&Bsm[cur][boff + j * 512];
        #pragma unroll
        for (int i = 0; i < 4; i++)
            #pragma unroll
            for (int j = 0; j < 4; j++)
                acc[i][j] = __builtin_amdgcn_mfma_f32_16x16x32_bf16(
                    af[i], bfr[j], acc[i][j], 0, 0, 0);
        __syncthreads();             // drains vmcnt(0) (prefetch) overlapped w/ MFMA
        cur ^= 1;
    }
    {   // last tile: no prefetch
        bf16x8 af[4], bfr[4];
        #pragma unroll
        for (int i = 0; i < 4; i++)
            af[i] = *(const bf16x8*)&Asm[cur][aoff + i * 512];
        #pragma unroll
        for (int j = 0; j < 4; j++)
            bfr[j] = *(const bf16x8*)&Bsm[cur][boff + j * 512];
        #pragma unroll
        for (int i = 0; i < 4; i++)
            #pragma unroll
            for (int j = 0; j < 4; j++)
                acc[i][j] = __builtin_amdgcn_mfma_f32_16x16x32_bf16(
                    af[i], bfr[j], acc[i][j], 0, 0, 0);
    }

    // Epilogue: C/D layout col = lane&15, row = (lane>>4)*4 + reg
    const int col0 = nbase + wc * 64 + mrow;
    #pragma unroll
    for (int i = 0; i < 4; i++) {
        const int rbase = wr * 64 + i * 16 + (lane >> 4) * 4;
        #pragma unroll
        for (int r = 0; r < 4; r++) {
            const int row  = rbase + r;
            const int grow = mbase + row;
            const int lab  = labs[row];
            float* orow = out + (size_t)grow * C_CLS;
            #pragma unroll
            for (int j = 0; j < 4; j++) {
                const int gc = col0 + j * 16;
                if (gc < C_CLS) {
                    float c = acc[i][j][r];
                    c = fminf(1.0f, fmaxf(-1.0f, c));
                    float v = c;
                    if (gc == lab) {
                        v = COS_M * c - SIN_M * sqrtf(fmaxf(0.0f, 1.0f - c * c));
                    }
                    orow[gc] = 30.0f * v;
                }
            }
        }
    }
    #undef STAGE
}

extern "C" void kernel_launch(void* const* d_in, const int* in_sizes, int n_in,
                              void* d_out, int out_size, void* d_ws, size_t ws_size,
                              hipStream_t stream) {
    const float* emb    = (const float*)d_in[0];
    const float* wgt    = (const float*)d_in[1];
    const int*   labels = (const int*)d_in[2];
    float*       out    = (float*)d_out;

    unsigned short* An = (unsigned short*)d_ws;                         // 1 MiB
    unsigned short* Wn = (unsigned short*)((char*)d_ws + (size_t)N_ROWS * DIM * 2);

    normalize_rows<<<N_ROWS / 4, 256, 0, stream>>>(emb, An, N_ROWS);
    normalize_rows<<<C_CLS / 4, 256, 0, stream>>>(wgt, Wn, C_CLS);
    arcface_gemm<<<dim3(MTILES * NPANEL), 512, 0, stream>>>(An, Wn, labels, out);
}

// Round 4
// 739.677 us; speedup vs baseline: 1.2365x; 1.0248x over previous
//
#include <hip/hip_runtime.h>
#include <cstdint>
#include <cstddef>

// ArcFace: e=l2norm(emb) [1024,512]; w=l2norm(weight) [100000,512];
// cos = clip(e@w^T, -1, 1); at (r, labels[r]): cos(theta+0.5); out = 30*logits.
// Margin closed form: cos(theta+M) = cosM*c - sinM*sqrt(1-c^2)  (theta in [0,pi]).
//
// GEMM: 128x256 tile, 8 waves (2Mx4N). Fragment-ordered LDS (zero bank
// conflicts, round-3 verified). K-loop uses the T3/T4 counted-vmcnt pipeline:
// 3 LDS buffers, prefetch depth 2, raw s_barrier, s_waitcnt vmcnt(3) in the
// main loop (NEVER 0) so prefetch loads stay in flight across barriers.
// Each stage = exactly 3 global_load_lds ops -> vmcnt math is exact.
// T5 setprio around the MFMA cluster. Bijective XCD swizzle for W-panel L2.

constexpr int N_ROWS  = 1024;
constexpr int DIM     = 512;
constexpr int C_CLS   = 100000;
constexpr int NPANEL  = 392;     // 256-col panels -> 100352 padded; 392 = 8*49
constexpr int MTILES  = 8;       // 1024 / 128

#define COS_M 0.87758256189037271612f
#define SIN_M 0.47942553860420300027f

typedef __attribute__((ext_vector_type(8))) __bf16 bf16x8;
typedef __attribute__((ext_vector_type(4))) float  floatx4;

__device__ inline unsigned short f2bf(float f) {
    unsigned int u = __float_as_uint(f);
    u += 0x7FFFu + ((u >> 16) & 1u);   // round-to-nearest-even
    return (unsigned short)(u >> 16);
}

__device__ inline float wave_reduce_sum(float v) {
    v += __shfl_xor(v, 32, 64);
    v += __shfl_xor(v, 16, 64);
    v += __shfl_xor(v, 8, 64);
    v += __shfl_xor(v, 4, 64);
    v += __shfl_xor(v, 2, 64);
    v += __shfl_xor(v, 1, 64);
    return v;
}

__device__ inline void async16(const void* g, void* l) {
    __builtin_amdgcn_global_load_lds(
        (const __attribute__((address_space(1))) void*)g,
        (__attribute__((address_space(3))) void*)l,
        16, 0, 0);
}

// One wave per row: l2-normalize f32 row -> bf16 row.
__global__ __launch_bounds__(256) void normalize_rows(
    const float* __restrict__ in, unsigned short* __restrict__ out, int rows) {
    int wave = (int)((blockIdx.x * 256u + threadIdx.x) >> 6);
    int lane = threadIdx.x & 63;
    if (wave >= rows) return;

    const float4* rp = (const float4*)(in + (size_t)wave * DIM);
    float4 x0 = rp[lane];        // cols 4*lane .. +4
    float4 x1 = rp[64 + lane];   // cols 256 + 4*lane .. +4
    float s = x0.x*x0.x + x0.y*x0.y + x0.z*x0.z + x0.w*x0.w
            + x1.x*x1.x + x1.y*x1.y + x1.z*x1.z + x1.w*x1.w;
    s = wave_reduce_sum(s);
    float inv = 1.0f / fmaxf(sqrtf(s), 1e-12f);
    unsigned short* orow = out + (size_t)wave * DIM;
    ushort4 o0, o1;
    o0.x = f2bf(x0.x * inv); o0.y = f2bf(x0.y * inv);
    o0.z = f2bf(x0.z * inv); o0.w = f2bf(x0.w * inv);
    o1.x = f2bf(x1.x * inv); o1.y = f2bf(x1.y * inv);
    o1.z = f2bf(x1.z * inv); o1.w = f2bf(x1.w * inv);
    ((ushort4*)orow)[lane]      = o0;
    ((ushort4*)orow)[64 + lane] = o1;
}

// 128x256 tile GEMM. A [1024,512] bf16 (pre-normalized), Wn [100000,512] bf16
// (pre-normalized), out = 30*clip(A@Wn^T) with margin at (r, labels[r]).
__global__ __launch_bounds__(512, 4) void arcface_gemm(
    const unsigned short* __restrict__ A,
    const unsigned short* __restrict__ Wn,
    const int* __restrict__ labels,
    float* __restrict__ out) {
    // Fragment-ordered LDS (ushort idx = group*512 + lane*8 for the reader).
    __shared__ unsigned short Asm[3][4096];  // 128 rows x 32 k, 8 KiB each
    __shared__ unsigned short Bsm[3][8192];  // 256 rows x 32 k, 16 KiB each
    __shared__ int labs[128];

    const int tid  = threadIdx.x;
    const int lane = tid & 63;
    const int wv   = tid >> 6;       // 0..7
    const int wr   = wv >> 2;        // 0..1  (64-row quadrant)
    const int wc   = wv & 3;         // 0..3  (64-col quadrant)
    const int mrow = lane & 15;

    // Bijective XCD swizzle: 3136 blocks = 8 XCDs x 392; 49 panels/XCD; the
    // 8 M-blocks of a panel are 8 apart in bid -> same XCD, adjacent dispatch.
    const int bid   = blockIdx.x;
    const int xcd   = bid & 7;
    const int s     = bid >> 3;                  // 0..391
    const int panel = xcd * (NPANEL / 8) + (s >> 3);
    const int mtile = s & 7;
    const int mbase = mtile * 128;
    const int nbase = panel * 256;

    if (tid < 128) labs[tid] = labels[mbase + tid];

    // ---- staging sources: lane l of group g loads row g*16+(l&15),
    //      k-chunk (l>>4); LDS dest is linear tid*16B == fragment order.
    const int sg    = tid >> 6;                  // group 0..7 (this wave's)
    const int smrow = lane & 15;
    const int skq   = lane >> 4;
    const unsigned short* aSrc = A + (size_t)(mbase + sg * 16 + smrow) * DIM + skq * 8;
    int brow0 = nbase + sg * 16 + smrow;
    int brow1 = nbase + 128 + sg * 16 + smrow;
    if (brow0 > C_CLS - 1) brow0 = C_CLS - 1;    // clamp padded cols (stores guarded)
    if (brow1 > C_CLS - 1) brow1 = C_CLS - 1;
    const unsigned short* bSrc0 = Wn + (size_t)brow0 * DIM + skq * 8;
    const unsigned short* bSrc1 = Wn + (size_t)brow1 * DIM + skq * 8;

    // Each STAGE = exactly 3 outstanding vmem ops (vmcnt bookkeeping).
    #define STAGE(buf, k0)                                         \
        do {                                                       \
            async16(aSrc  + (k0), &Asm[buf][tid * 8]);             \
            async16(bSrc0 + (k0), &Bsm[buf][tid * 8]);             \
            async16(bSrc1 + (k0), &Bsm[buf][4096 + tid * 8]);      \
        } while (0)

    floatx4 acc[4][4];
    #pragma unroll
    for (int i = 0; i < 4; i++)
        #pragma unroll
        for (int j = 0; j < 4; j++)
            acc[i][j] = (floatx4){0.f, 0.f, 0.f, 0.f};

    // Fragment read offsets (ushort idx): group (wr*4+i) / (wc*4+j), + lane*8.
    const int aoff = wr * 2048 + lane * 8;
    const int boff = wc * 2048 + lane * 8;

    #define COMPUTE(buf)                                                      \
        do {                                                                  \
            bf16x8 af[4], bfr[4];                                             \
            _Pragma("unroll")                                                 \
            for (int i = 0; i < 4; i++)                                       \
                af[i] = *(const bf16x8*)&Asm[buf][aoff + i * 512];            \
            _Pragma("unroll")                                                 \
            for (int j = 0; j < 4; j++)                                       \
                bfr[j] = *(const bf16x8*)&Bsm[buf][boff + j * 512];           \
            __builtin_amdgcn_s_setprio(1);                                    \
            _Pragma("unroll")                                                 \
            for (int i = 0; i < 4; i++)                                       \
                _Pragma("unroll")                                             \
                for (int j = 0; j < 4; j++)                                   \
                    acc[i][j] = __builtin_amdgcn_mfma_f32_16x16x32_bf16(      \
                        af[i], bfr[j], acc[i][j], 0, 0, 0);                   \
            __builtin_amdgcn_s_setprio(0);                                    \
        } while (0)

    // ---- counted-vmcnt pipeline: depth 2, 3 buffers, vmcnt(3) steady state.
    STAGE(0, 0);
    STAGE(1, 32);
    asm volatile("s_waitcnt lgkmcnt(0)" ::: "memory");   // labs ds_write visible

    #pragma unroll
    for (int t = 0; t < 14; t++) {
        asm volatile("s_waitcnt vmcnt(3)" ::: "memory"); // own tile-t loads landed
        asm volatile("s_barrier" ::: "memory");          // all waves: t landed, t-1 reads done
        STAGE((t + 2) % 3, (t + 2) * 32);                // into buffer freed at t-1
        COMPUTE(t % 3);
    }
    // t = 14: tiles 14,15 in flight (6 outstanding)
    asm volatile("s_waitcnt vmcnt(3)" ::: "memory");
    asm volatile("s_barrier" ::: "memory");
    COMPUTE(2);                                          // 14 % 3
    // t = 15: drain
    asm volatile("s_waitcnt vmcnt(0)" ::: "memory");
    asm volatile("s_barrier" ::: "memory");
    COMPUTE(0);                                          // 15 % 3

    // Epilogue: C/D layout col = lane&15, row = (lane>>4)*4 + reg
    const int col0 = nbase + wc * 64 + mrow;
    #pragma unroll
    for (int i = 0; i < 4; i++) {
        const int rbase = wr * 64 + i * 16 + (lane >> 4) * 4;
        #pragma unroll
        for (int r = 0; r < 4; r++) {
            const int row  = rbase + r;
            const int grow = mbase + row;
            const int lab  = labs[row];
            float* orow = out + (size_t)grow * C_CLS;
            #pragma unroll
            for (int j = 0; j < 4; j++) {
                const int gc = col0 + j * 16;
                if (gc < C_CLS) {
                    float c = acc[i][j][r];
                    c = fminf(1.0f, fmaxf(-1.0f, c));
                    float v = c;
                    if (gc == lab) {
                        v = COS_M * c - SIN_M * sqrtf(fmaxf(0.0f, 1.0f - c * c));
                    }
                    orow[gc] = 30.0f * v;
                }
            }
        }
    }
    #undef STAGE
    #undef COMPUTE
}

extern "C" void kernel_launch(void* const* d_in, const int* in_sizes, int n_in,
                              void* d_out, int out_size, void* d_ws, size_t ws_size,
                              hipStream_t stream) {
    const float* emb    = (const float*)d_in[0];
    const float* wgt    = (const float*)d_in[1];
    const int*   labels = (const int*)d_in[2];
    float*       out    = (float*)d_out;

    unsigned short* An = (unsigned short*)d_ws;                         // 1 MiB
    unsigned short* Wn = (unsigned short*)((char*)d_ws + (size_t)N_ROWS * DIM * 2);

    normalize_rows<<<N_ROWS / 4, 256, 0, stream>>>(emb, An, N_ROWS);
    normalize_rows<<<C_CLS / 4, 256, 0, stream>>>(wgt, Wn, C_CLS);
    arcface_gemm<<<dim3(MTILES * NPANEL), 512, 0, stream>>>(An, Wn, labels, out);
}